// Round 1
// baseline (147.438 us; speedup 1.0000x reference)
//
#include <hip/hip_runtime.h>
#include <math.h>

static constexpr float PHI_F = 1.61803398874989484820f;

union F4 { float4 v; float f[4]; };

__global__ __launch_bounds__(256) void liquid_echo_kernel(
    const float* __restrict__ x_real,
    const float* __restrict__ x_imag,
    const float* __restrict__ t,
    const float* __restrict__ mem_r,
    const float* __restrict__ mem_i,
    const float* __restrict__ w_query,
    const float* __restrict__ b_query,
    const float* __restrict__ w_osc,
    const float* __restrict__ b_osc,
    float* __restrict__ out_real,
    float* __restrict__ out_imag,
    float* __restrict__ out_alpha,
    int D)
{
    const int row = blockIdx.x;
    const int tid = threadIdx.x;
    const int d0  = tid << 2;                   // 4 elements per thread, D = 1024
    const size_t base = (size_t)row * (size_t)D + (size_t)d0;

    // One float4 per array per thread: every HBM byte read exactly once,
    // row tiles live in registers across both phases.
    F4 xr, xi, mr, mi, wq, bq, wo, bo;
    xr.v = *(const float4*)(x_real + base);
    xi.v = *(const float4*)(x_imag + base);
    mr.v = *(const float4*)(mem_r + base);
    mi.v = *(const float4*)(mem_i + base);
    wq.v = *(const float4*)(w_query + d0);
    bq.v = *(const float4*)(b_query + d0);
    wo.v = *(const float4*)(w_osc + d0);
    bo.v = *(const float4*)(b_osc + d0);

    // Phase 1: interference dot products
    float accr = 0.f, acci = 0.f;
#pragma unroll
    for (int j = 0; j < 4; ++j) {
        float inv = __builtin_amdgcn_rcpf(1.0f + fabsf(wq.f[j]));
        float th  = fmaf(xr.f[j], inv, bq.f[j]);
        float s, c;
        __sincosf(th, &s, &c);
        accr = fmaf(c, mr.f[j], fmaf(s, mi.f[j], accr));
        acci = fmaf(c, mi.f[j], fmaf(-s, mr.f[j], acci));
    }

    // 64-lane wave reduce, then combine 4 waves through LDS
#pragma unroll
    for (int off = 32; off > 0; off >>= 1) {
        accr += __shfl_down(accr, off, 64);
        acci += __shfl_down(acci, off, 64);
    }
    __shared__ float sred[8];
    const int wave = tid >> 6;
    const int lane = tid & 63;
    if (lane == 0) { sred[wave] = accr; sred[wave + 4] = acci; }
    __syncthreads();
    const float ir = (sred[0] + sred[1]) + (sred[2] + sred[3]);
    const float ii = (sred[4] + sred[5]) + (sred[6] + sred[7]);

    // alpha (computed redundantly by all threads; scale = sqrt(1024) = 32)
    const float mag   = sqrtf(fmaf(ir, ir, ii * ii));
    const float z     = fmaf(mag, 1.0f / 32.0f, -2.0f);
    const float norm  = __builtin_amdgcn_rcpf(1.0f + __expf(-z));   // sigmoid(z)
    const float alpha = __expf(norm - 1.0f);                        // exp(-(1-norm))
    const float beta  = 1.0f - alpha;
    const float tphi2 = 2.0f * PHI_F * t[row];

    // Phase 2: blend + oscillate. Angle-sum identity:
    //   evolved_real = cos(th_r + th_i), evolved_imag = sin(th_r + th_i)
    F4 er, ei;
#pragma unroll
    for (int j = 0; j < 4; ++j) {
        float br  = fmaf(alpha, xr.f[j], beta * mr.f[j]);
        float bi  = fmaf(alpha, xi.f[j], beta * mi.f[j]);
        float inv = __builtin_amdgcn_rcpf(1.0f + fabsf(wo.f[j]));
        float ths = fmaf(br + bi, inv, fmaf(2.0f, bo.f[j], tphi2));
        float s, c;
        __sincosf(ths, &s, &c);
        er.f[j] = c;
        ei.f[j] = s;
    }
    *(float4*)(out_real + base) = er.v;
    *(float4*)(out_imag + base) = ei.v;
    if (tid == 0) out_alpha[row] = alpha;
}

extern "C" void kernel_launch(void* const* d_in, const int* in_sizes, int n_in,
                              void* d_out, int out_size, void* d_ws, size_t ws_size,
                              hipStream_t stream) {
    const float* x_real = (const float*)d_in[0];
    const float* x_imag = (const float*)d_in[1];
    const float* t      = (const float*)d_in[2];
    const float* mem_r  = (const float*)d_in[3];
    const float* mem_i  = (const float*)d_in[4];
    const float* w_q    = (const float*)d_in[5];
    const float* b_q    = (const float*)d_in[6];
    const float* w_o    = (const float*)d_in[7];
    const float* b_o    = (const float*)d_in[8];

    const int B = in_sizes[2];   // 32768 (t has B elements)
    const int D = in_sizes[5];   // 1024  (w_query has D elements)

    float* out       = (float*)d_out;
    float* out_real  = out;
    float* out_imag  = out + (size_t)B * (size_t)D;
    float* out_alpha = out + 2ull * (size_t)B * (size_t)D;

    // One block per row: 256 threads x 4 f32 = D = 1024
    liquid_echo_kernel<<<B, 256, 0, stream>>>(
        x_real, x_imag, t, mem_r, mem_i, w_q, b_q, w_o, b_o,
        out_real, out_imag, out_alpha, D);
}